// Round 1
// baseline (327.144 us; speedup 1.0000x reference)
//
#include <hip/hip_runtime.h>
#include <math.h>

#define BATCH 32768
#define LW    200
#define CIN   6
#define KSZ   5
#define FLAT  196     // LW - KSZ + 1
#define NH1   50
#define NH2   30
#define NOUT  15

// Round-7: 8-way k-split (was 4-way). Structure is still wave-autonomous
// staging (private per-wave LDS slab, zero block barriers in the main loop),
// but each wave now owns a 24-output conv slice (wave 7: 28 -> 7*24+28=196).
// Grid 512 blocks x 512 threads = 4096 waves = 16 waves/CU = 4 waves/SIMD,
// doubling round-6's 2 waves/SIMD -- the kernel was latency-bound at
// VALUBusy 12.5% / Occupancy 17% with HBM at 8% of peak.
// LDS: waves 0..6 slabs [64][29] (28-col window), wave 7 [64][33] (32 cols);
// total 15104 floats = 59 KB < 64 KB static limit -> 2 blocks/CU.
// All slice bases 24*wv are 16B-aligned (off=0); wave 7's loads end exactly
// at col 200 (no OOB). Cross-wave fc1 reduction is a 2-level tree; all four
// __syncthreads execute on all 8 waves before any early return.

template<int NS>
__device__ __forceinline__ void conv_fc1_slice(
    const float* __restrict__ xw, float* __restrict__ tile, int lane,
    const float (&w)[CIN][KSZ], float bias,
    const float* __restrict__ w1, int kstart, float (&h1p)[NH1])
{
    constexpr int NLD = (NS + 4) / 4;   // float4 loads per lane per channel
    constexpr int TW  = NS + 5;         // odd stride -> conflict-free lane*TW reads

    // staging descriptors: float4 #g = lane + 64u of the [64 rows][NLD f4] tile
    int goff[NLD];   // global float offset (relative to xw, ch=0)
    int loff[NLD];   // LDS float offset within tile
#pragma unroll
    for (int u = 0; u < NLD; ++u) {
        int g   = lane + 64 * u;
        int row = g / NLD;              // const divisor -> magic-mul / shift
        int c4  = g - row * NLD;
        goff[u] = row * (CIN * LW) + 4 * c4;
        loff[u] = row * TW + 4 * c4;
    }

    float acc[NS];
#pragma unroll
    for (int i = 0; i < NS; ++i) acc[i] = bias;

    // prologue: issue channel 0 loads (NLD independent dwordx4)
    float4 buf[NLD];
#pragma unroll
    for (int u = 0; u < NLD; ++u)
        buf[u] = *(const float4*)(xw + goff[u]);

#pragma unroll
    for (int ch = 0; ch < CIN; ++ch) {
        // drain buf -> LDS (scalar writes; ~2-way banks = free)
#pragma unroll
        for (int u = 0; u < NLD; ++u) {
            float* dst = tile + loff[u];
            dst[0] = buf[u].x; dst[1] = buf[u].y; dst[2] = buf[u].z; dst[3] = buf[u].w;
        }
        // issue next channel's loads before consuming this one (hide latency)
        if (ch + 1 < CIN) {
#pragma unroll
            for (int u = 0; u < NLD; ++u)
                buf[u] = *(const float4*)(xw + (ch + 1) * LW + goff[u]);
        }
        // conv accumulate (batch = lane); odd TW -> conflict-free
        const float* row = tile + lane * TW;
        float x0 = row[0], x1 = row[1], x2 = row[2], x3 = row[3];
#pragma unroll
        for (int i = 0; i < NS; ++i) {
            float x4v = row[i + 4];
            float a = acc[i];
            a = fmaf(x0, w[ch][0], a);
            a = fmaf(x1, w[ch][1], a);
            a = fmaf(x2, w[ch][2], a);
            a = fmaf(x3, w[ch][3], a);
            a = fmaf(x4v, w[ch][4], a);
            acc[i] = a;
            x0 = x1; x1 = x2; x2 = x3; x3 = x4v;
        }
    }

    // fc1 partials: rows kstart..kstart+NS-1 of w1 (wave-uniform -> s_load)
#pragma unroll
    for (int ii = 0; ii < NS; ++ii) {
        const float* wrow = w1 + (size_t)(kstart + ii) * NH1;
        float c = acc[ii];
#pragma unroll
        for (int j = 0; j < NH1; ++j) h1p[j] = fmaf(c, wrow[j], h1p[j]);
    }
}

__global__ __launch_bounds__(512, 4) void fused_kernel(
    const float* __restrict__ x,
    const float* __restrict__ cw, const float* __restrict__ cb,
    const float* __restrict__ w1, const float* __restrict__ b1,
    const float* __restrict__ w2, const float* __restrict__ b2,
    const float* __restrict__ w3, const float* __restrict__ b3,
    float* __restrict__ out)
{
    // waves 0..6: 64*29 floats each; wave 7: 64*33. Total 15104 floats = 59 KB.
    __shared__ float xs[15104];

    const int tid  = threadIdx.x;
    const int wv   = __builtin_amdgcn_readfirstlane(tid >> 6);  // SGPR wave id
    const int lane = tid & 63;
    const int b    = blockIdx.x * 64 + lane;
    const int kstart = 24 * wv;            // conv-output slice base (== tile base col)

    float* tile = xs + wv * (64 * 29);     // this wave's private slab

    // conv weights / bias: uniform -> scalar regs
    float w[CIN][KSZ];
#pragma unroll
    for (int c = 0; c < CIN; ++c)
#pragma unroll
        for (int k = 0; k < KSZ; ++k) w[c][k] = cw[c * KSZ + k];
    const float bias = cb[0];

    const float* xw = x + (size_t)blockIdx.x * 64 * (CIN * LW) + kstart;

    float h1p[NH1];
#pragma unroll
    for (int j = 0; j < NH1; ++j) h1p[j] = 0.f;

    if (wv == 7)
        conv_fc1_slice<28>(xw, tile, lane, w, bias, w1, kstart, h1p);
    else
        conv_fc1_slice<24>(xw, tile, lane, w, bias, w1, kstart, h1p);

    // ---- cross-wave tree reduction (all barriers hit by all 8 waves) ----
    __syncthreads();                       // all tiles dead; safe to reuse xs
    float* part = xs;                      // 4 slabs [64][53] = 13568 floats
    if (wv >= 4) {
#pragma unroll
        for (int j = 0; j < NH1; ++j)
            part[(wv - 4) * (64 * 53) + lane * 53 + j] = h1p[j];
    }
    __syncthreads();
    if (wv < 4) {
#pragma unroll
        for (int j = 0; j < NH1; ++j)
            h1p[j] += part[wv * (64 * 53) + lane * 53 + j];
    }
    __syncthreads();                       // stage-B reads done before overwrite
    if (wv >= 1 && wv < 4) {
#pragma unroll
        for (int j = 0; j < NH1; ++j)
            part[(wv - 1) * (64 * 53) + lane * 53 + j] = h1p[j];
    }
    __syncthreads();
    if (wv != 0) return;                   // free SIMD slots; wave 0 runs the tail

    float h1[NH1];
#pragma unroll
    for (int j = 0; j < NH1; ++j) {
        float s = h1p[j]
                + part[lane * 53 + j]
                + part[64 * 53 + lane * 53 + j]
                + part[2 * 64 * 53 + lane * 53 + j]
                + b1[j];
        h1[j] = fmaxf(s, 0.f);
    }

    // fc2
    float h2[NH2];
#pragma unroll
    for (int j = 0; j < NH2; ++j) h2[j] = b2[j];
#pragma unroll
    for (int k = 0; k < NH1; ++k) {
        float hk = h1[k];
        const float* row = w2 + k * NH2;              // uniform -> s_load
#pragma unroll
        for (int j = 0; j < NH2; ++j) h2[j] = fmaf(hk, row[j], h2[j]);
    }
#pragma unroll
    for (int j = 0; j < NH2; ++j) h2[j] = fmaxf(h2[j], 0.f);

    // fc3 (no relu)
    float o[NOUT];
#pragma unroll
    for (int j = 0; j < NOUT; ++j) o[j] = b3[j];
#pragma unroll
    for (int k = 0; k < NH2; ++k) {
        float hk = h2[k];
        const float* row = w3 + k * NOUT;             // uniform -> s_load
#pragma unroll
        for (int j = 0; j < NOUT; ++j) o[j] = fmaf(hk, row[j], o[j]);
    }

    // ---- closest proper rotation (Davenport K-matrix, f32 Jacobi) ----
    {
        float r00 = o[0], r01 = o[1], r02 = o[2];
        float r10 = o[3], r11 = o[4], r12 = o[5];
        float r20 = o[6], r21 = o[7], r22 = o[8];

        float A[4][4], V[4][4];
        A[0][0] = r00 + r11 + r22;
        A[1][1] = r00 - r11 - r22;
        A[2][2] = r11 - r00 - r22;
        A[3][3] = r22 - r00 - r11;
        A[0][1] = A[1][0] = r21 - r12;
        A[0][2] = A[2][0] = r02 - r20;
        A[0][3] = A[3][0] = r10 - r01;
        A[1][2] = A[2][1] = r01 + r10;
        A[1][3] = A[3][1] = r02 + r20;
        A[2][3] = A[3][2] = r12 + r21;
#pragma unroll
        for (int i = 0; i < 4; ++i)
#pragma unroll
            for (int j = 0; j < 4; ++j) V[i][j] = (i == j) ? 1.f : 0.f;

        const int pr[6][2] = {{0,1},{0,2},{0,3},{1,2},{1,3},{2,3}};
        for (int sweep = 0; sweep < 7; ++sweep) {
#pragma unroll
            for (int pi = 0; pi < 6; ++pi) {
                const int p = pr[pi][0], q = pr[pi][1];
                float apq = A[p][q];
                if (fabsf(apq) > 1e-20f) {
                    float theta = (A[q][q] - A[p][p]) / (2.f * apq);
                    float t = copysignf(1.f, theta) / (fabsf(theta) + sqrtf(1.f + theta * theta));
                    float c = rsqrtf(1.f + t * t);
                    float s = t * c;
#pragma unroll
                    for (int k = 0; k < 4; ++k) {
                        float akp = A[k][p], akq = A[k][q];
                        A[k][p] = c * akp - s * akq;
                        A[k][q] = s * akp + c * akq;
                    }
#pragma unroll
                    for (int k = 0; k < 4; ++k) {
                        float apk = A[p][k], aqk = A[q][k];
                        A[p][k] = c * apk - s * aqk;
                        A[q][k] = s * apk + c * aqk;
                    }
#pragma unroll
                    for (int k = 0; k < 4; ++k) {
                        float vkp = V[k][p], vkq = V[k][q];
                        V[k][p] = c * vkp - s * vkq;
                        V[k][q] = s * vkp + c * vkq;
                    }
                }
            }
        }

        int best = 0;
        float bl = A[0][0];
#pragma unroll
        for (int i = 1; i < 4; ++i)
            if (A[i][i] > bl) { bl = A[i][i]; best = i; }

        float vw = V[0][best], vx = V[1][best], vy = V[2][best], vz = V[3][best];
        float inv = rsqrtf(vw * vw + vx * vx + vy * vy + vz * vz);
        vw *= inv; vx *= inv; vy *= inv; vz *= inv;

        float xx = vx * vx, yy = vy * vy, zz = vz * vz;
        float xy = vx * vy, xz = vx * vz, yz = vy * vz;
        float wx = vw * vx, wy = vw * vy, wz = vw * vz;

        float* ob = out + (long)b * NOUT;
        ob[0]  = 1.f - 2.f * (yy + zz);
        ob[1]  = 2.f * (xy - wz);
        ob[2]  = 2.f * (xz + wy);
        ob[3]  = 2.f * (xy + wz);
        ob[4]  = 1.f - 2.f * (xx + zz);
        ob[5]  = 2.f * (yz - wx);
        ob[6]  = 2.f * (xz - wy);
        ob[7]  = 2.f * (yz + wx);
        ob[8]  = 1.f - 2.f * (xx + yy);
        ob[9]  = o[9];
        ob[10] = o[10];
        ob[11] = o[11];
        ob[12] = o[12];
        ob[13] = o[13];
        ob[14] = o[14];
    }
}

extern "C" void kernel_launch(void* const* d_in, const int* in_sizes, int n_in,
                              void* d_out, int out_size, void* d_ws, size_t ws_size,
                              hipStream_t stream) {
    const float* x  = (const float*)d_in[0];
    const float* cw = (const float*)d_in[1];
    const float* cb = (const float*)d_in[2];
    const float* w1 = (const float*)d_in[3];
    const float* b1 = (const float*)d_in[4];
    const float* w2 = (const float*)d_in[5];
    const float* b2 = (const float*)d_in[6];
    const float* w3 = (const float*)d_in[7];
    const float* b3 = (const float*)d_in[8];
    float* outp = (float*)d_out;

    fused_kernel<<<BATCH / 64, 512, 0, stream>>>(x, cw, cb, w1, b1, w2, b2, w3, b3, outp);
}

// Round 2
// 319.780 us; speedup vs baseline: 1.0230x; 1.0230x over previous
//
#include <hip/hip_runtime.h>
#include <math.h>

#define BATCH 32768
#define LW    200
#define CIN   6
#define KSZ   5
#define FLAT  196     // LW - KSZ + 1
#define NH1   50
#define NH2   30
#define NOUT  15

#define NS    28      // conv outputs per wave (7 waves x 28 = 196)
#define NLD   8       // float4 loads per lane per channel (64 rows x 8 f4 / 64 lanes)
#define TW    33      // LDS tile row stride (floats); odd -> conflict-free lane*TW reads

// Round-8: 7-way k-split, single code path. Round-7's regression was
// (a) __launch_bounds__(512,4) acting as min-4-BLOCKS/CU -> 64-VGPR cap ->
//     ~54 MB/dispatch scratch spill (WRITE_SIZE 1920->55680 KB), and
// (b) h1p[50] initialized before the conv -> +50 regs live range.
// This round: 448 threads = 7 waves, each owning exactly 28 conv outputs
// (196 = 7*28, no template duality); slab [64][32 cols] per wave, NLD=8
// (g/8 = shift, no magic-div); h1p comes alive only after the conv.
// LDS 59136 B -> 2 blocks/CU -> 14 waves/CU = 3.5 waves/SIMD (round-6 had 2).
// No __launch_bounds__ second arg: regalloc free, expect ~120 VGPR, no spill.
__global__ __launch_bounds__(448) void fused_kernel(
    const float* __restrict__ x,
    const float* __restrict__ cw, const float* __restrict__ cb,
    const float* __restrict__ w1, const float* __restrict__ b1,
    const float* __restrict__ w2, const float* __restrict__ b2,
    const float* __restrict__ w3, const float* __restrict__ b3,
    float* __restrict__ out)
{
    __shared__ float xs[7 * 64 * TW];      // 14784 floats = 59136 B

    const int tid  = threadIdx.x;
    const int wv   = __builtin_amdgcn_readfirstlane(tid >> 6);  // SGPR wave id 0..6
    const int lane = tid & 63;
    const int b    = blockIdx.x * 64 + lane;
    const int kstart = NS * wv;            // conv-output slice base == tile base col
                                           // (28*wv: 16B-aligned; wv=6 covers cols 168..200)

    float* tile = xs + wv * (64 * TW);     // this wave's private slab

    // conv weights / bias: uniform -> scalar regs
    float w[CIN][KSZ];
#pragma unroll
    for (int c = 0; c < CIN; ++c)
#pragma unroll
        for (int k = 0; k < KSZ; ++k) w[c][k] = cw[c * KSZ + k];
    const float bias = cb[0];

    // staging descriptors: float4 #g = lane + 64u of the [64 rows][8 f4] tile
    int goff[NLD];   // global float offset (relative to xw, ch=0)
    int loff[NLD];   // LDS float offset within tile
#pragma unroll
    for (int u = 0; u < NLD; ++u) {
        int g   = lane + 64 * u;
        int row = g >> 3;                  // NLD=8 -> shift, no magic-div
        int c4  = g & 7;
        goff[u] = row * (CIN * LW) + 4 * c4;
        loff[u] = row * TW + 4 * c4;
    }
    const float* xw = x + (size_t)blockIdx.x * 64 * (CIN * LW) + kstart;

    float acc[NS];
#pragma unroll
    for (int i = 0; i < NS; ++i) acc[i] = bias;

    // prologue: issue channel 0 loads (8 independent dwordx4)
    float4 buf[NLD];
#pragma unroll
    for (int u = 0; u < NLD; ++u)
        buf[u] = *(const float4*)(xw + goff[u]);

#pragma unroll
    for (int ch = 0; ch < CIN; ++ch) {
        // drain buf -> LDS (scalar writes; <=2-way banks = free)
#pragma unroll
        for (int u = 0; u < NLD; ++u) {
            float* dst = tile + loff[u];
            dst[0] = buf[u].x; dst[1] = buf[u].y; dst[2] = buf[u].z; dst[3] = buf[u].w;
        }
        // issue next channel's loads before consuming this one (hide latency)
        if (ch + 1 < CIN) {
#pragma unroll
            for (int u = 0; u < NLD; ++u)
                buf[u] = *(const float4*)(xw + (ch + 1) * LW + goff[u]);
        }
        // conv accumulate (batch = lane); stride TW=33 odd -> conflict-free
        const float* row = tile + lane * TW;
        float x0 = row[0], x1 = row[1], x2 = row[2], x3 = row[3];
#pragma unroll
        for (int i = 0; i < NS; ++i) {
            float x4v = row[i + 4];
            float a = acc[i];
            a = fmaf(x0, w[ch][0], a);
            a = fmaf(x1, w[ch][1], a);
            a = fmaf(x2, w[ch][2], a);
            a = fmaf(x3, w[ch][3], a);
            a = fmaf(x4v, w[ch][4], a);
            acc[i] = a;
            x0 = x1; x1 = x2; x2 = x3; x3 = x4v;
        }
    }

    // ---- fc1 partials: rows kstart..kstart+27 of w1 (wave-uniform -> s_load) ----
    // h1p comes alive only HERE (after buf/goff/w die) -> low peak pressure.
    float h1p[NH1];
#pragma unroll
    for (int j = 0; j < NH1; ++j) h1p[j] = 0.f;
#pragma unroll
    for (int ii = 0; ii < NS; ++ii) {
        const float* wrow = w1 + (size_t)(kstart + ii) * NH1;
        float c = acc[ii];
#pragma unroll
        for (int j = 0; j < NH1; ++j) h1p[j] = fmaf(c, wrow[j], h1p[j]);
    }

    // ---- cross-wave tree reduction (all barriers hit by all 7 waves) ----
    // capacity: at most 3 slabs of [64][53] = 10176 floats <= 14784.
    __syncthreads();                       // all tiles dead; safe to reuse xs
    float* part = xs;
    if (wv >= 4) {                         // waves 4,5,6 publish
#pragma unroll
        for (int j = 0; j < NH1; ++j)
            part[(wv - 4) * (64 * 53) + lane * 53 + j] = h1p[j];
    }
    __syncthreads();
    if (wv < 3) {                          // 0+=4, 1+=5, 2+=6 (wave 3 idle)
#pragma unroll
        for (int j = 0; j < NH1; ++j)
            h1p[j] += part[wv * (64 * 53) + lane * 53 + j];
    }
    __syncthreads();                       // stage-B reads done before overwrite
    if (wv >= 1 && wv < 4) {               // waves 1,2,3 publish their sums
#pragma unroll
        for (int j = 0; j < NH1; ++j)
            part[(wv - 1) * (64 * 53) + lane * 53 + j] = h1p[j];
    }
    __syncthreads();
    if (wv != 0) return;                   // free SIMD slots; wave 0 runs the tail

    float h1[NH1];
#pragma unroll
    for (int j = 0; j < NH1; ++j) {
        float s = h1p[j]
                + part[lane * 53 + j]
                + part[64 * 53 + lane * 53 + j]
                + part[2 * 64 * 53 + lane * 53 + j]
                + b1[j];
        h1[j] = fmaxf(s, 0.f);
    }

    // fc2
    float h2[NH2];
#pragma unroll
    for (int j = 0; j < NH2; ++j) h2[j] = b2[j];
#pragma unroll
    for (int k = 0; k < NH1; ++k) {
        float hk = h1[k];
        const float* row = w2 + k * NH2;              // uniform -> s_load
#pragma unroll
        for (int j = 0; j < NH2; ++j) h2[j] = fmaf(hk, row[j], h2[j]);
    }
#pragma unroll
    for (int j = 0; j < NH2; ++j) h2[j] = fmaxf(h2[j], 0.f);

    // fc3 (no relu)
    float o[NOUT];
#pragma unroll
    for (int j = 0; j < NOUT; ++j) o[j] = b3[j];
#pragma unroll
    for (int k = 0; k < NH2; ++k) {
        float hk = h2[k];
        const float* row = w3 + k * NOUT;             // uniform -> s_load
#pragma unroll
        for (int j = 0; j < NOUT; ++j) o[j] = fmaf(hk, row[j], o[j]);
    }

    // ---- closest proper rotation (Davenport K-matrix, f32 Jacobi) ----
    {
        float r00 = o[0], r01 = o[1], r02 = o[2];
        float r10 = o[3], r11 = o[4], r12 = o[5];
        float r20 = o[6], r21 = o[7], r22 = o[8];

        float A[4][4], V[4][4];
        A[0][0] = r00 + r11 + r22;
        A[1][1] = r00 - r11 - r22;
        A[2][2] = r11 - r00 - r22;
        A[3][3] = r22 - r00 - r11;
        A[0][1] = A[1][0] = r21 - r12;
        A[0][2] = A[2][0] = r02 - r20;
        A[0][3] = A[3][0] = r10 - r01;
        A[1][2] = A[2][1] = r01 + r10;
        A[1][3] = A[3][1] = r02 + r20;
        A[2][3] = A[3][2] = r12 + r21;
#pragma unroll
        for (int i = 0; i < 4; ++i)
#pragma unroll
            for (int j = 0; j < 4; ++j) V[i][j] = (i == j) ? 1.f : 0.f;

        const int pr[6][2] = {{0,1},{0,2},{0,3},{1,2},{1,3},{2,3}};
        for (int sweep = 0; sweep < 7; ++sweep) {
#pragma unroll
            for (int pi = 0; pi < 6; ++pi) {
                const int p = pr[pi][0], q = pr[pi][1];
                float apq = A[p][q];
                if (fabsf(apq) > 1e-20f) {
                    float theta = (A[q][q] - A[p][p]) / (2.f * apq);
                    float t = copysignf(1.f, theta) / (fabsf(theta) + sqrtf(1.f + theta * theta));
                    float c = rsqrtf(1.f + t * t);
                    float s = t * c;
#pragma unroll
                    for (int k = 0; k < 4; ++k) {
                        float akp = A[k][p], akq = A[k][q];
                        A[k][p] = c * akp - s * akq;
                        A[k][q] = s * akp + c * akq;
                    }
#pragma unroll
                    for (int k = 0; k < 4; ++k) {
                        float apk = A[p][k], aqk = A[q][k];
                        A[p][k] = c * apk - s * aqk;
                        A[q][k] = s * apk + c * aqk;
                    }
#pragma unroll
                    for (int k = 0; k < 4; ++k) {
                        float vkp = V[k][p], vkq = V[k][q];
                        V[k][p] = c * vkp - s * vkq;
                        V[k][q] = s * vkp + c * vkq;
                    }
                }
            }
        }

        int best = 0;
        float bl = A[0][0];
#pragma unroll
        for (int i = 1; i < 4; ++i)
            if (A[i][i] > bl) { bl = A[i][i]; best = i; }

        float vw = V[0][best], vx = V[1][best], vy = V[2][best], vz = V[3][best];
        float inv = rsqrtf(vw * vw + vx * vx + vy * vy + vz * vz);
        vw *= inv; vx *= inv; vy *= inv; vz *= inv;

        float xx = vx * vx, yy = vy * vy, zz = vz * vz;
        float xy = vx * vy, xz = vx * vz, yz = vy * vz;
        float wx = vw * vx, wy = vw * vy, wz = vw * vz;

        float* ob = out + (long)b * NOUT;
        ob[0]  = 1.f - 2.f * (yy + zz);
        ob[1]  = 2.f * (xy - wz);
        ob[2]  = 2.f * (xz + wy);
        ob[3]  = 2.f * (xy + wz);
        ob[4]  = 1.f - 2.f * (xx + zz);
        ob[5]  = 2.f * (yz - wx);
        ob[6]  = 2.f * (xz - wy);
        ob[7]  = 2.f * (yz + wx);
        ob[8]  = 1.f - 2.f * (xx + yy);
        ob[9]  = o[9];
        ob[10] = o[10];
        ob[11] = o[11];
        ob[12] = o[12];
        ob[13] = o[13];
        ob[14] = o[14];
    }
}

extern "C" void kernel_launch(void* const* d_in, const int* in_sizes, int n_in,
                              void* d_out, int out_size, void* d_ws, size_t ws_size,
                              hipStream_t stream) {
    const float* x  = (const float*)d_in[0];
    const float* cw = (const float*)d_in[1];
    const float* cb = (const float*)d_in[2];
    const float* w1 = (const float*)d_in[3];
    const float* b1 = (const float*)d_in[4];
    const float* w2 = (const float*)d_in[5];
    const float* b2 = (const float*)d_in[6];
    const float* w3 = (const float*)d_in[7];
    const float* b3 = (const float*)d_in[8];
    float* outp = (float*)d_out;

    fused_kernel<<<BATCH / 64, 448, 0, stream>>>(x, cw, cb, w1, b1, w2, b2, w3, b3, outp);
}